// Round 17
// baseline (175.908 us; speedup 1.0000x reference)
//
#include <hip/hip_runtime.h>
#include <hip/hip_bf16.h>

#define NN 50000
#define NE 800000
#define ND 64
#define ED 32
#define HID 64
#define NL 2
#define IN_MSG 96   // ND + ED
#define IN_UPD 128  // ND + HID

#define W1_LD 104   // ushort stride for W1^T rows (96+8), 208B
#define MSG_LD 72   // ushort stride for msg/h scratch rows, 144B
#define UPD_LD 136  // ushort stride for node comb rows (128+8), 272B

#define NBLK 512            // 2 blocks/CU (proven best for msg)
#define WPB 4
#define TOTW (NBLK * WPB)   // 2048 waves
#define NGRP (NE / 32)      // 25000 groups of 32 edges
#define NB_SCAN 196         // ceil(NN/256)

typedef __attribute__((ext_vector_type(8))) short short8;  // 8 bf16 = 4 VGPR
typedef __attribute__((ext_vector_type(4))) float f32x4;

__device__ inline ushort bf16r(float f) {  // fp32 -> bf16 RNE via HW cvt
    __hip_bfloat16 h = __float2bfloat16(f);
    return *reinterpret_cast<ushort*>(&h);
}
__device__ inline float b2f(unsigned u) {
    union { unsigned u; float f; } x; x.u = u << 16; return x.f;
}
__device__ inline short8 pk8(float4 a, float4 b) {
    short8 r;
    r[0] = (short)bf16r(a.x); r[1] = (short)bf16r(a.y);
    r[2] = (short)bf16r(a.z); r[3] = (short)bf16r(a.w);
    r[4] = (short)bf16r(b.x); r[5] = (short)bf16r(b.y);
    r[6] = (short)bf16r(b.z); r[7] = (short)bf16r(b.w);
    return r;
}
__device__ inline uint2 pack4(float4 v) {
    return make_uint2((unsigned)bf16r(v.x) | ((unsigned)bf16r(v.y) << 16),
                      (unsigned)bf16r(v.z) | ((unsigned)bf16r(v.w) << 16));
}
__device__ inline uint2 pkacc(f32x4 a) {   // 4 f32 -> 4 bf16
    return make_uint2((unsigned)bf16r(a[0]) | ((unsigned)bf16r(a[1]) << 16),
                      (unsigned)bf16r(a[2]) | ((unsigned)bf16r(a[3]) << 16));
}

// ============================ dst-CSR build =================================
__global__ __launch_bounds__(256) void hist_kernel(const int* __restrict__ dst,
                                                   int* __restrict__ cnt)
{
    const int i = blockIdx.x * 256 + threadIdx.x;   // grid exact
    atomicAdd(&cnt[dst[i]], 1);
}

__global__ __launch_bounds__(256) void scanA_kernel(const int* __restrict__ cnt,
                                                    int* __restrict__ off,
                                                    int* __restrict__ bsum)
{
    __shared__ int buf[256];
    const int t = threadIdx.x;
    const int i = blockIdx.x * 256 + t;
    const int v = (i < NN) ? cnt[i] : 0;
    buf[t] = v;
    __syncthreads();
    #pragma unroll
    for (int d = 1; d < 256; d <<= 1) {
        const int x = (t >= d) ? buf[t - d] : 0;
        __syncthreads();
        buf[t] += x;
        __syncthreads();
    }
    if (i < NN) off[i] = buf[t] - v;
    if (t == 255) bsum[blockIdx.x] = buf[255];
}

__global__ __launch_bounds__(256) void scanB_kernel(int* __restrict__ bsum)
{
    __shared__ int buf[256];
    const int t = threadIdx.x;
    buf[t] = (t < NB_SCAN) ? bsum[t] : 0;
    __syncthreads();
    #pragma unroll
    for (int d = 1; d < 256; d <<= 1) {
        const int x = (t >= d) ? buf[t - d] : 0;
        __syncthreads();
        buf[t] += x;
        __syncthreads();
    }
    if (t < NB_SCAN) bsum[t] = buf[t];
}

__global__ __launch_bounds__(256) void scanC_kernel(const int* __restrict__ bsum,
                                                    int* __restrict__ off,
                                                    int* __restrict__ cursor)
{
    const int b = blockIdx.x;
    const int i = b * 256 + threadIdx.x;
    const int boff = (b > 0) ? bsum[b - 1] : 0;
    if (i < NN) {
        const int e = off[i] + boff;
        off[i] = e;
        cursor[i] = e;
    }
    if (i == 0) off[NN] = NE;
}

// scatter (src,dst) AND bf16-converted edge features to the dst-sorted
// position; zero agg. ef is read coalesced here (original order) so msg
// never has to gather it randomly.
__global__ __launch_bounds__(256)
void fill_kernel(const float* __restrict__ ef,
                 const int* __restrict__ src,
                 const int* __restrict__ dst,
                 int* __restrict__ cursor,
                 int2* __restrict__ sdsort,
                 ushort* __restrict__ efsort,
                 float4* __restrict__ agg4)
{
    __shared__ int sPos[256];
    const int tid = threadIdx.x;
    const int i = blockIdx.x * 256 + tid;       // grid exact: 3125*256 = NE
    const int d = dst[i];
    const int pos = atomicAdd(&cursor[d], 1);
    sdsort[pos] = make_int2(src[i], d);
    sPos[tid] = pos;
    agg4[i] = make_float4(0.f, 0.f, 0.f, 0.f);  // NE = NN*HID/4 exactly
    __syncthreads();
    const int w = tid >> 6, l = tid & 63;
    const int c = l & 7;                        // 16B chunk within row
    #pragma unroll
    for (int it = 0; it < 8; ++it) {
        const int rloc = w * 64 + (l >> 3) + 8 * it;   // wave-private 64 rows
        const size_t r = (size_t)blockIdx.x * 256 + rloc;
        const float4 v = reinterpret_cast<const float4*>(ef)[r * 8 + c];
        const uint2 pk = pack4(v);
        *reinterpret_cast<uint2*>(efsort + (size_t)sPos[rloc] * 32 + c * 4) = pk;
    }
}

// ======================= edge message MLP (MFMA) ============================
// Swapped MFMA operands; dst-sorted segmented reduce; ef consumed as a
// coalesced pre-converted bf16 stream (efsort) -> random gathers only for nf.
template <int SORTED>
__global__ __launch_bounds__(256, 2)
void msg_kernel(const float* __restrict__ nf,
                const float* __restrict__ ef,
                const float* __restrict__ w1,
                const float* __restrict__ b1,
                const float* __restrict__ w2,
                const float* __restrict__ b2,
                const int* __restrict__ src,
                const int* __restrict__ dst,
                const int2* __restrict__ sdsort,
                const ushort* __restrict__ efsort,
                float* __restrict__ agg,
                float* __restrict__ deg)
{
    __shared__ __align__(16) ushort sW1t[NL][64][W1_LD];  // 26,624 B
    __shared__ __align__(16) ushort sMS[WPB][32][MSG_LD]; // 18,432 B
    __shared__ __align__(16) float sB1f[NL][64];
    __shared__ __align__(16) float sB2f[64];              // => ~45.8 KB

    const int tid = threadIdx.x;
    const int w  = tid >> 6;
    const int l  = tid & 63;
    const int lr = l & 15;
    const int lg = l >> 4;

    // ---- one-time stage: W1^T (padded) + biases ----
    {
        const int k16 = tid >> 4, n0 = (tid & 15) * 4;
        #pragma unroll
        for (int lay = 0; lay < NL; ++lay)
            #pragma unroll
            for (int it = 0; it < 6; ++it) {
                const int k = k16 + 16 * it;   // 0..95
                const float4 v = *reinterpret_cast<const float4*>(
                    w1 + ((size_t)lay * IN_MSG + k) * HID + n0);
                sW1t[lay][n0 + 0][k] = bf16r(v.x);
                sW1t[lay][n0 + 1][k] = bf16r(v.y);
                sW1t[lay][n0 + 2][k] = bf16r(v.z);
                sW1t[lay][n0 + 3][k] = bf16r(v.w);
            }
        if (tid < NL * 64) sB1f[tid >> 6][tid & 63] = b1[tid];
        if (tid < 64) sB2f[tid] = b2[tid] + b2[HID + tid];
    }
    // ---- W2 fragments in registers (both layers) ----
    short8 w2f[NL][4][2];
    #pragma unroll
    for (int lay = 0; lay < NL; ++lay)
        #pragma unroll
        for (int nt = 0; nt < 4; ++nt)
            #pragma unroll
            for (int ks = 0; ks < 2; ++ks) {
                short8 t;
                #pragma unroll
                for (int j = 0; j < 8; ++j)
                    t[j] = (short)bf16r(
                        w2[((size_t)lay * HID + ks * 32 + 8 * lg + j) * HID + nt * 16 + lr]);
                w2f[lay][nt][ks] = t;
            }
    __syncthreads();

    const float4* nfr = reinterpret_cast<const float4*>(nf);  // 16 float4 / row
    const float4* efr = reinterpret_cast<const float4*>(ef);  //  8 float4 / row (fallback)

    // ---- prologue: idx gen 0 and 1, features gen 0 ----
    int g = blockIdx.x * WPB + w;
    int sv = 0, dv = 0, sn = 0, dn = 0;
    if (l < 32) {
        if (SORTED) { const int2 t = sdsort[(size_t)g * 32 + l]; sv = t.x; dv = t.y; }
        else        { sv = src[(size_t)g * 32 + l]; dv = dst[(size_t)g * 32 + l]; }
    }
    {
        const int gn = g + TOTW;
        if (gn < NGRP && l < 32) {
            if (SORTED) { const int2 t = sdsort[(size_t)gn * 32 + l]; sn = t.x; dn = t.y; }
            else        { sn = src[(size_t)gn * 32 + l]; dn = dst[(size_t)gn * 32 + l]; }
        }
    }
    float4 nfv[2][4];
    short8 efv[2];          // SORTED path: pre-converted bf16 frag
    float4 efvf[2][2];      // fallback path: raw float gathers
    #pragma unroll
    for (int mt = 0; mt < 2; ++mt) {
        const int s = __shfl(sv, mt * 16 + lr);
        const float4* p = nfr + (size_t)s * 16;
        nfv[mt][0] = p[2 * lg];     nfv[mt][1] = p[2 * lg + 1];
        nfv[mt][2] = p[8 + 2 * lg]; nfv[mt][3] = p[9 + 2 * lg];
        if (SORTED) {
            efv[mt] = *reinterpret_cast<const short8*>(
                efsort + (size_t)(g * 32 + mt * 16 + lr) * 32 + 8 * lg);
        } else {
            const float4* q = efr + (size_t)(g * 32 + mt * 16 + lr) * 8;
            efvf[mt][0] = q[2 * lg];
            efvf[mt][1] = q[2 * lg + 1];
        }
    }

    #pragma unroll 1
    while (g < NGRP) {
        const int gn  = g + TOTW;
        const int gnn = g + 2 * TOTW;
        const bool more = (gn < NGRP);

        short8 cmbA[2][3];
        #pragma unroll
        for (int mt = 0; mt < 2; ++mt) {
            cmbA[mt][0] = pk8(nfv[mt][0], nfv[mt][1]);
            cmbA[mt][1] = pk8(nfv[mt][2], nfv[mt][3]);
            cmbA[mt][2] = SORTED ? efv[mt] : pk8(efvf[mt][0], efvf[mt][1]);
        }

        int sn2 = 0, dn2 = 0;
        if (gnn < NGRP && l < 32) {
            if (SORTED) { const int2 t = sdsort[(size_t)gnn * 32 + l]; sn2 = t.x; dn2 = t.y; }
            else        { sn2 = src[(size_t)gnn * 32 + l]; dn2 = dst[(size_t)gnn * 32 + l]; }
        }
        float4 nfn[2][4];
        short8 efn[2];
        float4 efnf[2][2];
        if (more) {
            #pragma unroll
            for (int mt = 0; mt < 2; ++mt) {
                if (SORTED) {
                    efn[mt] = *reinterpret_cast<const short8*>(
                        efsort + (size_t)(gn * 32 + mt * 16 + lr) * 32 + 8 * lg);
                } else {
                    const float4* q = efr + (size_t)(gn * 32 + mt * 16 + lr) * 8;
                    efnf[mt][0] = q[2 * lg];
                    efnf[mt][1] = q[2 * lg + 1];
                }
                const int s = __shfl(sn, mt * 16 + lr);
                const float4* p = nfr + (size_t)s * 16;
                nfn[mt][0] = p[2 * lg];     nfn[mt][1] = p[2 * lg + 1];
                nfn[mt][2] = p[8 + 2 * lg]; nfn[mt][3] = p[9 + 2 * lg];
            }
        }

        f32x4 msg[2][4];
        #pragma unroll
        for (int nt = 0; nt < 4; ++nt) {
            const f32x4 b2v = *reinterpret_cast<const f32x4*>(&sB2f[nt * 16 + 4 * lg]);
            msg[0][nt] = b2v;
            msg[1][nt] = b2v;
        }

        #pragma unroll
        for (int lay = 0; lay < NL; ++lay) {
            f32x4 acc[2][4];
            #pragma unroll
            for (int nt = 0; nt < 4; ++nt) {
                const f32x4 bv = *reinterpret_cast<const f32x4*>(&sB1f[lay][nt * 16 + 4 * lg]);
                acc[0][nt] = bv;
                acc[1][nt] = bv;
            }
            __builtin_amdgcn_s_setprio(1);
            #pragma unroll
            for (int ks = 0; ks < 3; ++ks)
                #pragma unroll
                for (int nt = 0; nt < 4; ++nt) {
                    const short8 Bw = *reinterpret_cast<const short8*>(
                        &sW1t[lay][nt * 16 + lr][ks * 32 + 8 * lg]);
                    acc[0][nt] = __builtin_amdgcn_mfma_f32_16x16x32_bf16(Bw, cmbA[0][ks], acc[0][nt], 0, 0, 0);
                    acc[1][nt] = __builtin_amdgcn_mfma_f32_16x16x32_bf16(Bw, cmbA[1][ks], acc[1][nt], 0, 0, 0);
                }
            __builtin_amdgcn_s_setprio(0);
            #pragma unroll
            for (int mt = 0; mt < 2; ++mt)
                #pragma unroll
                for (int nt = 0; nt < 4; ++nt) {
                    f32x4 a = acc[mt][nt];
                    a[0] = fmaxf(a[0], 0.0f); a[1] = fmaxf(a[1], 0.0f);
                    a[2] = fmaxf(a[2], 0.0f); a[3] = fmaxf(a[3], 0.0f);
                    *reinterpret_cast<uint2*>(&sMS[w][mt * 16 + lr][nt * 16 + 4 * lg]) = pkacc(a);
                }
            short8 hA[2][2];
            #pragma unroll
            for (int mt = 0; mt < 2; ++mt)
                #pragma unroll
                for (int ks = 0; ks < 2; ++ks)
                    hA[mt][ks] = *reinterpret_cast<const short8*>(
                        &sMS[w][mt * 16 + lr][ks * 32 + 8 * lg]);
            __builtin_amdgcn_s_setprio(1);
            #pragma unroll
            for (int ks = 0; ks < 2; ++ks)
                #pragma unroll
                for (int nt = 0; nt < 4; ++nt) {
                    msg[0][nt] = __builtin_amdgcn_mfma_f32_16x16x32_bf16(w2f[lay][nt][ks], hA[0][ks], msg[0][nt], 0, 0, 0);
                    msg[1][nt] = __builtin_amdgcn_mfma_f32_16x16x32_bf16(w2f[lay][nt][ks], hA[1][ks], msg[1][nt], 0, 0, 0);
                }
            __builtin_amdgcn_s_setprio(0);
        }

        // msg -> LDS rows (packed b64), then reduce / flush
        #pragma unroll
        for (int mt = 0; mt < 2; ++mt)
            #pragma unroll
            for (int nt = 0; nt < 4; ++nt)
                *reinterpret_cast<uint2*>(&sMS[w][mt * 16 + lr][nt * 16 + 4 * lg]) = pkacc(msg[mt][nt]);

        if (SORTED) {
            float acc = 0.0f;
            int dr = __builtin_amdgcn_readlane(dv, 0);
            #pragma unroll
            for (int r = 0; r < 32; ++r) {
                acc += b2f((unsigned)sMS[w][r][l]);
                const int drn = (r < 31) ? __builtin_amdgcn_readlane(dv, r + 1) : -1;
                if (r == 31 || dr != drn) {
                    atomicAdd(&agg[(size_t)dr * HID + l], acc);
                    acc = 0.0f;
                }
                dr = drn;
            }
        } else {
            #pragma unroll
            for (int r = 0; r < 32; ++r) {
                const int dr = __builtin_amdgcn_readlane(dv, r);
                atomicAdd(&agg[(size_t)dr * HID + l], b2f((unsigned)sMS[w][r][l]));
            }
            if (l < 32) atomicAdd(&deg[dv], 1.0f);
        }

        sv = sn; dv = dn; sn = sn2; dn = dn2;
        #pragma unroll
        for (int mt = 0; mt < 2; ++mt) {
            #pragma unroll
            for (int i = 0; i < 4; ++i) nfv[mt][i] = nfn[mt][i];
            if (SORTED) { efv[mt] = efn[mt]; }
            else { efvf[mt][0] = efnf[mt][0]; efvf[mt][1] = efnf[mt][1]; }
        }
        g = gn;
    }
}

// ===== node update: 128-thread blocks (2 waves x 32 nodes) ====
template <int USE_OFF>
__global__ __launch_bounds__(128, 2)
void node_update_kernel(const float* __restrict__ nf,
                        const float* __restrict__ agg,
                        const int* __restrict__ off,
                        const float* __restrict__ degf,
                        const float* __restrict__ uw1,
                        const float* __restrict__ ub1,
                        const float* __restrict__ uw2,
                        const float* __restrict__ ub2,
                        float* __restrict__ out)
{
    __shared__ __align__(16) ushort sAct[2][32][UPD_LD];
    __shared__ __align__(16) ushort sW1t[64][UPD_LD];
    __shared__ __align__(16) ushort sW2t[64][MSG_LD];
    __shared__ float sUB1[64], sUB2[64];

    const int tid = threadIdx.x;
    const int w  = tid >> 6;      // 0..1
    const int l  = tid & 63;
    const int lr = l & 15;
    const int lg = l >> 4;

    {   // weight stage (128 threads)
        const int k16 = tid >> 4, n0 = (tid & 15) * 4;
        #pragma unroll
        for (int it = 0; it < 16; ++it) {
            const int k = k16 + 8 * it;    // 0..127
            const float4 v = *reinterpret_cast<const float4*>(uw1 + (size_t)k * HID + n0);
            sW1t[n0 + 0][k] = bf16r(v.x);
            sW1t[n0 + 1][k] = bf16r(v.y);
            sW1t[n0 + 2][k] = bf16r(v.z);
            sW1t[n0 + 3][k] = bf16r(v.w);
        }
        #pragma unroll
        for (int it = 0; it < 8; ++it) {
            const int k = k16 + 8 * it;    // 0..63
            const float4 v = *reinterpret_cast<const float4*>(uw2 + (size_t)k * ND + n0);
            sW2t[n0 + 0][k] = bf16r(v.x);
            sW2t[n0 + 1][k] = bf16r(v.y);
            sW2t[n0 + 2][k] = bf16r(v.z);
            sW2t[n0 + 3][k] = bf16r(v.w);
        }
        if (tid < 64) { sUB1[tid] = ub1[tid]; sUB2[tid] = ub2[tid]; }
    }

    const int nbase = blockIdx.x * 64 + w * 32;
    float invv = 0.0f;
    if (l < 32) {
        const int n = min(nbase + l, NN - 1);
        const float d = USE_OFF ? (float)(off[n + 1] - off[n]) : degf[n];
        invv = 1.0f / (d + 1e-8f);
    }

    #pragma unroll
    for (int it = 0; it < 8; ++it) {
        const int row = lg + 4 * it;
        const int n = min(nbase + row, NN - 1);
        const float4 v = reinterpret_cast<const float4*>(nf + (size_t)n * ND)[lr];
        *reinterpret_cast<uint2*>(&sAct[w][row][lr * 4]) = pack4(v);
    }
    #pragma unroll
    for (int it = 0; it < 8; ++it) {
        const int row = lg + 4 * it;
        const int n = min(nbase + row, NN - 1);
        const float iv = __shfl(invv, row);
        float4 v = reinterpret_cast<const float4*>(agg + (size_t)n * HID)[lr];
        v.x *= iv; v.y *= iv; v.z *= iv; v.w *= iv;
        *reinterpret_cast<uint2*>(&sAct[w][row][ND + lr * 4]) = pack4(v);
    }
    __syncthreads();

    short8 A[2][4];
    #pragma unroll
    for (int mt = 0; mt < 2; ++mt)
        #pragma unroll
        for (int ks = 0; ks < 4; ++ks)
            A[mt][ks] = *reinterpret_cast<const short8*>(&sAct[w][mt * 16 + lr][ks * 32 + 8 * lg]);
    #pragma unroll
    for (int nt = 0; nt < 4; ++nt) {
        const int cB = nt * 16 + lr;
        short8 B[4];
        #pragma unroll
        for (int ks = 0; ks < 4; ++ks)
            B[ks] = *reinterpret_cast<const short8*>(&sW1t[cB][ks * 32 + 8 * lg]);
        const float bv = sUB1[cB];
        #pragma unroll
        for (int mt = 0; mt < 2; ++mt) {
            f32x4 acc = (f32x4){bv, bv, bv, bv};
            #pragma unroll
            for (int ks = 0; ks < 4; ++ks)
                acc = __builtin_amdgcn_mfma_f32_16x16x32_bf16(A[mt][ks], B[ks], acc, 0, 0, 0);
            const int rH = mt * 16 + 4 * lg;
            #pragma unroll
            for (int r = 0; r < 4; ++r)
                sAct[w][rH + r][cB] = bf16r(fmaxf(acc[r], 0.0f));
        }
    }

    f32x4 o[2][4];
    #pragma unroll
    for (int nt = 0; nt < 4; ++nt) {
        const float v = sUB2[nt * 16 + lr];
        o[0][nt] = (f32x4){v, v, v, v};
        o[1][nt] = (f32x4){v, v, v, v};
    }
    #pragma unroll
    for (int mt = 0; mt < 2; ++mt) {
        const short8 A0 = *reinterpret_cast<const short8*>(&sAct[w][mt * 16 + lr][ 0 + 8 * lg]);
        const short8 A1 = *reinterpret_cast<const short8*>(&sAct[w][mt * 16 + lr][32 + 8 * lg]);
        #pragma unroll
        for (int nt = 0; nt < 4; ++nt) {
            const int cB = nt * 16 + lr;
            const short8 B0 = *reinterpret_cast<const short8*>(&sW2t[cB][ 0 + 8 * lg]);
            const short8 B1 = *reinterpret_cast<const short8*>(&sW2t[cB][32 + 8 * lg]);
            o[mt][nt] = __builtin_amdgcn_mfma_f32_16x16x32_bf16(A0, B0, o[mt][nt], 0, 0, 0);
            o[mt][nt] = __builtin_amdgcn_mfma_f32_16x16x32_bf16(A1, B1, o[mt][nt], 0, 0, 0);
        }
    }

    #pragma unroll
    for (int mt = 0; mt < 2; ++mt)
        #pragma unroll
        for (int r = 0; r < 4; ++r) {
            const int n = nbase + mt * 16 + 4 * lg + r;
            if (n < NN) {
                float* rowp = out + (size_t)n * ND;
                #pragma unroll
                for (int nt = 0; nt < 4; ++nt)
                    rowp[nt * 16 + lr] = o[mt][nt][r];
            }
        }
}

extern "C" void kernel_launch(void* const* d_in, const int* in_sizes, int n_in,
                              void* d_out, int out_size, void* d_ws, size_t ws_size,
                              hipStream_t stream)
{
    const float* nf  = (const float*)d_in[0];
    const float* ef  = (const float*)d_in[1];
    const float* w1  = (const float*)d_in[2];
    const float* b1  = (const float*)d_in[3];
    const float* w2  = (const float*)d_in[4];
    const float* b2  = (const float*)d_in[5];
    const float* uw1 = (const float*)d_in[6];
    const float* ub1 = (const float*)d_in[7];
    const float* uw2 = (const float*)d_in[8];
    const float* ub2 = (const float*)d_in[9];
    const int*   src = (const int*)d_in[10];
    const int*   dst = (const int*)d_in[11];
    float* out = (float*)d_out;

    constexpr size_t SDB  = (size_t)NE * 8;            //  6.4 MB (int2 per edge)
    constexpr size_t EFB  = (size_t)NE * 64;           // 51.2 MB (bf16 ef rows)
    constexpr size_t OFFB = (size_t)(NN + 1) * 4 + 12;
    constexpr size_t CNTB = (size_t)NN * 4;
    constexpr size_t BSUMB = 1024;
    constexpr size_t AGGB = (size_t)NN * HID * 4;      // 12.8 MB
    constexpr size_t NEED = SDB + EFB + OFFB + CNTB + BSUMB + AGGB;

    if (ws_size >= NEED) {
        char* p = (char*)d_ws;
        int2*   sdsort = (int2*)p;         p += SDB;
        ushort* efsort = (ushort*)p;       p += EFB;
        int*    off    = (int*)p;          p += OFFB;
        int*    cnt    = (int*)p;          p += CNTB;   // also cursor
        int*    bsum   = (int*)p;          p += BSUMB;
        float*  agg    = (float*)p;

        (void)hipMemsetAsync(cnt, 0, CNTB, stream);
        hist_kernel<<<NE / 256, 256, 0, stream>>>(dst, cnt);
        scanA_kernel<<<NB_SCAN, 256, 0, stream>>>(cnt, off, bsum);
        scanB_kernel<<<1, 256, 0, stream>>>(bsum);
        scanC_kernel<<<NB_SCAN, 256, 0, stream>>>(bsum, off, cnt);
        fill_kernel<<<NE / 256, 256, 0, stream>>>(ef, src, dst, cnt, sdsort,
                                                  efsort, (float4*)agg);
        msg_kernel<1><<<NBLK, 256, 0, stream>>>(nf, ef, w1, b1, w2, b2, src, dst,
                                                sdsort, efsort, agg, nullptr);
        node_update_kernel<1><<<(NN + 63) / 64, 128, 0, stream>>>(
            nf, agg, off, nullptr, uw1, ub1, uw2, ub2, out);
    } else {
        float* agg = (float*)d_ws;                    // [NN][HID]
        float* deg = agg + (size_t)NN * HID;          // [NN]
        (void)hipMemsetAsync(d_ws, 0, ((size_t)NN * HID + NN) * sizeof(float), stream);
        msg_kernel<0><<<NBLK, 256, 0, stream>>>(nf, ef, w1, b1, w2, b2, src, dst,
                                                nullptr, nullptr, agg, deg);
        node_update_kernel<0><<<(NN + 63) / 64, 128, 0, stream>>>(
            nf, agg, nullptr, deg, uw1, ub1, uw2, ub2, out);
    }
}

// Round 18
// 168.076 us; speedup vs baseline: 1.0466x; 1.0466x over previous
//
#include <hip/hip_runtime.h>
#include <hip/hip_bf16.h>

#define NN 50000
#define NE 800000
#define ND 64
#define ED 32
#define HID 64
#define NL 2
#define IN_MSG 96   // ND + ED
#define IN_UPD 128  // ND + HID

#define W1_LD 104   // ushort stride for W1^T rows (96+8), 208B
#define MSG_LD 72   // ushort stride for msg/h scratch rows, 144B
#define UPD_LD 136  // ushort stride for node comb rows (128+8), 272B

#define NBLK 512            // 2 blocks/CU (proven best for msg)
#define WPB 4
#define TOTW (NBLK * WPB)   // 2048 waves
#define NGRP (NE / 32)      // 25000 groups of 32 edges
#define NB_SCAN 196         // ceil(NN/256)

typedef __attribute__((ext_vector_type(8))) short short8;  // 8 bf16 = 4 VGPR
typedef __attribute__((ext_vector_type(4))) float f32x4;

__device__ inline ushort bf16r(float f) {  // fp32 -> bf16 RNE via HW cvt
    __hip_bfloat16 h = __float2bfloat16(f);
    return *reinterpret_cast<ushort*>(&h);
}
__device__ inline float b2f(unsigned u) {
    union { unsigned u; float f; } x; x.u = u << 16; return x.f;
}
__device__ inline short8 pk8(float4 a, float4 b) {
    short8 r;
    r[0] = (short)bf16r(a.x); r[1] = (short)bf16r(a.y);
    r[2] = (short)bf16r(a.z); r[3] = (short)bf16r(a.w);
    r[4] = (short)bf16r(b.x); r[5] = (short)bf16r(b.y);
    r[6] = (short)bf16r(b.z); r[7] = (short)bf16r(b.w);
    return r;
}
__device__ inline uint2 pack4(float4 v) {
    return make_uint2((unsigned)bf16r(v.x) | ((unsigned)bf16r(v.y) << 16),
                      (unsigned)bf16r(v.z) | ((unsigned)bf16r(v.w) << 16));
}
__device__ inline uint2 pkacc(f32x4 a) {   // 4 f32 -> 4 bf16
    return make_uint2((unsigned)bf16r(a[0]) | ((unsigned)bf16r(a[1]) << 16),
                      (unsigned)bf16r(a[2]) | ((unsigned)bf16r(a[3]) << 16));
}

// ============================ dst-CSR build =================================
__global__ __launch_bounds__(256) void hist_kernel(const int* __restrict__ dst,
                                                   int* __restrict__ cnt)
{
    const int i = blockIdx.x * 256 + threadIdx.x;   // grid exact
    atomicAdd(&cnt[dst[i]], 1);
}

__global__ __launch_bounds__(256) void scanA_kernel(const int* __restrict__ cnt,
                                                    int* __restrict__ off,
                                                    int* __restrict__ bsum)
{
    __shared__ int buf[256];
    const int t = threadIdx.x;
    const int i = blockIdx.x * 256 + t;
    const int v = (i < NN) ? cnt[i] : 0;
    buf[t] = v;
    __syncthreads();
    #pragma unroll
    for (int d = 1; d < 256; d <<= 1) {
        const int x = (t >= d) ? buf[t - d] : 0;
        __syncthreads();
        buf[t] += x;
        __syncthreads();
    }
    if (i < NN) off[i] = buf[t] - v;
    if (t == 255) bsum[blockIdx.x] = buf[255];
}

// scanC with scanB folded in: every block redundantly scans the 196 block
// sums in LDS (trivial) and takes its prefix -> one fewer dispatch.
__global__ __launch_bounds__(256) void scanC_kernel(const int* __restrict__ bsum,
                                                    int* __restrict__ off,
                                                    int* __restrict__ cursor)
{
    __shared__ int buf[256];
    const int t = threadIdx.x;
    buf[t] = (t < NB_SCAN) ? bsum[t] : 0;
    __syncthreads();
    #pragma unroll
    for (int d = 1; d < 256; d <<= 1) {
        const int x = (t >= d) ? buf[t - d] : 0;
        __syncthreads();
        buf[t] += x;
        __syncthreads();
    }
    const int b = blockIdx.x;
    const int boff = (b > 0) ? buf[b - 1] : 0;
    const int i = b * 256 + t;
    if (i < NN) {
        const int e = off[i] + boff;
        off[i] = e;
        cursor[i] = e;
    }
    if (i == 0) off[NN] = NE;
}

// scatter into dst-sorted order + zero agg (drops a separate memset launch)
__global__ __launch_bounds__(256) void fill_kernel(const int* __restrict__ src,
                                                   const int* __restrict__ dst,
                                                   int* __restrict__ cursor,
                                                   int4* __restrict__ esd,
                                                   float4* __restrict__ agg4)
{
    const int i = blockIdx.x * 256 + threadIdx.x;   // grid exact: 3125*256 = NE
    const int d = dst[i];
    const int pos = atomicAdd(&cursor[d], 1);
    esd[pos] = make_int4(i, src[i], d, 0);
    agg4[i] = make_float4(0.f, 0.f, 0.f, 0.f);      // NE = NN*HID/4 exactly
}

// ======================= edge message MLP (MFMA) ============================
// Swapped MFMA operands; dst-sorted segmented reduce; (256,2) codegen
// protects the 2-generation register pipeline (VGPR 124).
template <int SORTED>
__global__ __launch_bounds__(256, 2)
void msg_kernel(const float* __restrict__ nf,
                const float* __restrict__ ef,
                const float* __restrict__ w1,
                const float* __restrict__ b1,
                const float* __restrict__ w2,
                const float* __restrict__ b2,
                const int* __restrict__ src,
                const int* __restrict__ dst,
                const int4* __restrict__ esd,
                float* __restrict__ agg,
                float* __restrict__ deg)
{
    __shared__ __align__(16) ushort sW1t[NL][64][W1_LD];  // 26,624 B
    __shared__ __align__(16) ushort sMS[WPB][32][MSG_LD]; // 18,432 B
    __shared__ __align__(16) float sB1f[NL][64];
    __shared__ __align__(16) float sB2f[64];              // => ~45.8 KB

    const int tid = threadIdx.x;
    const int w  = tid >> 6;
    const int l  = tid & 63;
    const int lr = l & 15;
    const int lg = l >> 4;

    // ---- one-time stage: W1^T (padded) + biases ----
    {
        const int k16 = tid >> 4, n0 = (tid & 15) * 4;
        #pragma unroll
        for (int lay = 0; lay < NL; ++lay)
            #pragma unroll
            for (int it = 0; it < 6; ++it) {
                const int k = k16 + 16 * it;   // 0..95
                const float4 v = *reinterpret_cast<const float4*>(
                    w1 + ((size_t)lay * IN_MSG + k) * HID + n0);
                sW1t[lay][n0 + 0][k] = bf16r(v.x);
                sW1t[lay][n0 + 1][k] = bf16r(v.y);
                sW1t[lay][n0 + 2][k] = bf16r(v.z);
                sW1t[lay][n0 + 3][k] = bf16r(v.w);
            }
        if (tid < NL * 64) sB1f[tid >> 6][tid & 63] = b1[tid];
        if (tid < 64) sB2f[tid] = b2[tid] + b2[HID + tid];
    }
    // ---- W2 fragments in registers (both layers) ----
    short8 w2f[NL][4][2];
    #pragma unroll
    for (int lay = 0; lay < NL; ++lay)
        #pragma unroll
        for (int nt = 0; nt < 4; ++nt)
            #pragma unroll
            for (int ks = 0; ks < 2; ++ks) {
                short8 t;
                #pragma unroll
                for (int j = 0; j < 8; ++j)
                    t[j] = (short)bf16r(
                        w2[((size_t)lay * HID + ks * 32 + 8 * lg + j) * HID + nt * 16 + lr]);
                w2f[lay][nt][ks] = t;
            }
    __syncthreads();

    const float4* nfr = reinterpret_cast<const float4*>(nf);  // 16 float4 / row
    const float4* efr = reinterpret_cast<const float4*>(ef);  //  8 float4 / row

    // ---- prologue: idx gen 0 and 1, features gen 0 ----
    int g = blockIdx.x * WPB + w;
    int ev = 0, sv = 0, dv = 0;
    int en = 0, sn = 0, dn = 0;
    if (l < 32) {
        if (SORTED) { const int4 t = esd[(size_t)g * 32 + l]; ev = t.x; sv = t.y; dv = t.z; }
        else        { sv = src[(size_t)g * 32 + l]; dv = dst[(size_t)g * 32 + l]; }
    }
    {
        const int gn = g + TOTW;
        if (gn < NGRP && l < 32) {
            if (SORTED) { const int4 t = esd[(size_t)gn * 32 + l]; en = t.x; sn = t.y; dn = t.z; }
            else        { sn = src[(size_t)gn * 32 + l]; dn = dst[(size_t)gn * 32 + l]; }
        }
    }
    float4 nfv[2][4], efv[2][2];
    #pragma unroll
    for (int mt = 0; mt < 2; ++mt) {
        const int s = __shfl(sv, mt * 16 + lr);
        const float4* p = nfr + (size_t)s * 16;
        nfv[mt][0] = p[2 * lg];     nfv[mt][1] = p[2 * lg + 1];
        nfv[mt][2] = p[8 + 2 * lg]; nfv[mt][3] = p[9 + 2 * lg];
        const int e = SORTED ? __shfl(ev, mt * 16 + lr) : (g * 32 + mt * 16 + lr);
        const float4* q = efr + (size_t)e * 8;
        efv[mt][0] = q[2 * lg];
        efv[mt][1] = q[2 * lg + 1];
    }

    #pragma unroll 1
    while (g < NGRP) {
        const int gn  = g + TOTW;
        const int gnn = g + 2 * TOTW;
        const bool more = (gn < NGRP);

        short8 cmbA[2][3];
        #pragma unroll
        for (int mt = 0; mt < 2; ++mt) {
            cmbA[mt][0] = pk8(nfv[mt][0], nfv[mt][1]);
            cmbA[mt][1] = pk8(nfv[mt][2], nfv[mt][3]);
            cmbA[mt][2] = pk8(efv[mt][0], efv[mt][1]);
        }

        int en2 = 0, sn2 = 0, dn2 = 0;
        if (gnn < NGRP && l < 32) {
            if (SORTED) { const int4 t = esd[(size_t)gnn * 32 + l]; en2 = t.x; sn2 = t.y; dn2 = t.z; }
            else        { sn2 = src[(size_t)gnn * 32 + l]; dn2 = dst[(size_t)gnn * 32 + l]; }
        }
        float4 nfn[2][4], efn[2][2];
        if (more) {
            #pragma unroll
            for (int mt = 0; mt < 2; ++mt) {
                const int e = SORTED ? __shfl(en, mt * 16 + lr) : (gn * 32 + mt * 16 + lr);
                const float4* q = efr + (size_t)e * 8;
                efn[mt][0] = q[2 * lg];
                efn[mt][1] = q[2 * lg + 1];
                const int s = __shfl(sn, mt * 16 + lr);
                const float4* p = nfr + (size_t)s * 16;
                nfn[mt][0] = p[2 * lg];     nfn[mt][1] = p[2 * lg + 1];
                nfn[mt][2] = p[8 + 2 * lg]; nfn[mt][3] = p[9 + 2 * lg];
            }
        }
        // Pin: all next-generation loads must ISSUE before anything below.
        __builtin_amdgcn_sched_barrier(0);

        f32x4 msg[2][4];
        #pragma unroll
        for (int nt = 0; nt < 4; ++nt) {
            const f32x4 b2v = *reinterpret_cast<const f32x4*>(&sB2f[nt * 16 + 4 * lg]);
            msg[0][nt] = b2v;
            msg[1][nt] = b2v;
        }

        #pragma unroll
        for (int lay = 0; lay < NL; ++lay) {
            f32x4 acc[2][4];
            #pragma unroll
            for (int nt = 0; nt < 4; ++nt) {
                const f32x4 bv = *reinterpret_cast<const f32x4*>(&sB1f[lay][nt * 16 + 4 * lg]);
                acc[0][nt] = bv;
                acc[1][nt] = bv;
            }
            __builtin_amdgcn_s_setprio(1);
            #pragma unroll
            for (int ks = 0; ks < 3; ++ks)
                #pragma unroll
                for (int nt = 0; nt < 4; ++nt) {
                    const short8 Bw = *reinterpret_cast<const short8*>(
                        &sW1t[lay][nt * 16 + lr][ks * 32 + 8 * lg]);
                    acc[0][nt] = __builtin_amdgcn_mfma_f32_16x16x32_bf16(Bw, cmbA[0][ks], acc[0][nt], 0, 0, 0);
                    acc[1][nt] = __builtin_amdgcn_mfma_f32_16x16x32_bf16(Bw, cmbA[1][ks], acc[1][nt], 0, 0, 0);
                }
            __builtin_amdgcn_s_setprio(0);
            #pragma unroll
            for (int mt = 0; mt < 2; ++mt)
                #pragma unroll
                for (int nt = 0; nt < 4; ++nt) {
                    f32x4 a = acc[mt][nt];
                    a[0] = fmaxf(a[0], 0.0f); a[1] = fmaxf(a[1], 0.0f);
                    a[2] = fmaxf(a[2], 0.0f); a[3] = fmaxf(a[3], 0.0f);
                    *reinterpret_cast<uint2*>(&sMS[w][mt * 16 + lr][nt * 16 + 4 * lg]) = pkacc(a);
                }
            short8 hA[2][2];
            #pragma unroll
            for (int mt = 0; mt < 2; ++mt)
                #pragma unroll
                for (int ks = 0; ks < 2; ++ks)
                    hA[mt][ks] = *reinterpret_cast<const short8*>(
                        &sMS[w][mt * 16 + lr][ks * 32 + 8 * lg]);
            __builtin_amdgcn_s_setprio(1);
            #pragma unroll
            for (int ks = 0; ks < 2; ++ks)
                #pragma unroll
                for (int nt = 0; nt < 4; ++nt) {
                    msg[0][nt] = __builtin_amdgcn_mfma_f32_16x16x32_bf16(w2f[lay][nt][ks], hA[0][ks], msg[0][nt], 0, 0, 0);
                    msg[1][nt] = __builtin_amdgcn_mfma_f32_16x16x32_bf16(w2f[lay][nt][ks], hA[1][ks], msg[1][nt], 0, 0, 0);
                }
            __builtin_amdgcn_s_setprio(0);
        }

        // msg -> LDS rows (packed b64), then reduce / flush
        #pragma unroll
        for (int mt = 0; mt < 2; ++mt)
            #pragma unroll
            for (int nt = 0; nt < 4; ++nt)
                *reinterpret_cast<uint2*>(&sMS[w][mt * 16 + lr][nt * 16 + 4 * lg]) = pkacc(msg[mt][nt]);

        if (SORTED) {
            float acc = 0.0f;
            int dr = __builtin_amdgcn_readlane(dv, 0);
            #pragma unroll
            for (int r = 0; r < 32; ++r) {
                acc += b2f((unsigned)sMS[w][r][l]);
                const int drn = (r < 31) ? __builtin_amdgcn_readlane(dv, r + 1) : -1;
                if (r == 31 || dr != drn) {
                    atomicAdd(&agg[(size_t)dr * HID + l], acc);
                    acc = 0.0f;
                }
                dr = drn;
            }
        } else {
            #pragma unroll
            for (int r = 0; r < 32; ++r) {
                const int dr = __builtin_amdgcn_readlane(dv, r);
                atomicAdd(&agg[(size_t)dr * HID + l], b2f((unsigned)sMS[w][r][l]));
            }
            if (l < 32) atomicAdd(&deg[dv], 1.0f);
        }

        ev = en; sv = sn; dv = dn;
        en = en2; sn = sn2; dn = dn2;
        #pragma unroll
        for (int mt = 0; mt < 2; ++mt) {
            #pragma unroll
            for (int i = 0; i < 4; ++i) nfv[mt][i] = nfn[mt][i];
            efv[mt][0] = efn[mt][0]; efv[mt][1] = efn[mt][1];
        }
        g = gn;
    }
}

// ===== node update: 128-thread blocks (2 waves x 32 nodes) ====
template <int USE_OFF>
__global__ __launch_bounds__(128, 2)
void node_update_kernel(const float* __restrict__ nf,
                        const float* __restrict__ agg,
                        const int* __restrict__ off,
                        const float* __restrict__ degf,
                        const float* __restrict__ uw1,
                        const float* __restrict__ ub1,
                        const float* __restrict__ uw2,
                        const float* __restrict__ ub2,
                        float* __restrict__ out)
{
    __shared__ __align__(16) ushort sAct[2][32][UPD_LD];
    __shared__ __align__(16) ushort sW1t[64][UPD_LD];
    __shared__ __align__(16) ushort sW2t[64][MSG_LD];
    __shared__ float sUB1[64], sUB2[64];

    const int tid = threadIdx.x;
    const int w  = tid >> 6;      // 0..1
    const int l  = tid & 63;
    const int lr = l & 15;
    const int lg = l >> 4;

    {   // weight stage (128 threads)
        const int k16 = tid >> 4, n0 = (tid & 15) * 4;
        #pragma unroll
        for (int it = 0; it < 16; ++it) {
            const int k = k16 + 8 * it;    // 0..127
            const float4 v = *reinterpret_cast<const float4*>(uw1 + (size_t)k * HID + n0);
            sW1t[n0 + 0][k] = bf16r(v.x);
            sW1t[n0 + 1][k] = bf16r(v.y);
            sW1t[n0 + 2][k] = bf16r(v.z);
            sW1t[n0 + 3][k] = bf16r(v.w);
        }
        #pragma unroll
        for (int it = 0; it < 8; ++it) {
            const int k = k16 + 8 * it;    // 0..63
            const float4 v = *reinterpret_cast<const float4*>(uw2 + (size_t)k * ND + n0);
            sW2t[n0 + 0][k] = bf16r(v.x);
            sW2t[n0 + 1][k] = bf16r(v.y);
            sW2t[n0 + 2][k] = bf16r(v.z);
            sW2t[n0 + 3][k] = bf16r(v.w);
        }
        if (tid < 64) { sUB1[tid] = ub1[tid]; sUB2[tid] = ub2[tid]; }
    }

    const int nbase = blockIdx.x * 64 + w * 32;
    float invv = 0.0f;
    if (l < 32) {
        const int n = min(nbase + l, NN - 1);
        const float d = USE_OFF ? (float)(off[n + 1] - off[n]) : degf[n];
        invv = 1.0f / (d + 1e-8f);
    }

    #pragma unroll
    for (int it = 0; it < 8; ++it) {
        const int row = lg + 4 * it;
        const int n = min(nbase + row, NN - 1);
        const float4 v = reinterpret_cast<const float4*>(nf + (size_t)n * ND)[lr];
        *reinterpret_cast<uint2*>(&sAct[w][row][lr * 4]) = pack4(v);
    }
    #pragma unroll
    for (int it = 0; it < 8; ++it) {
        const int row = lg + 4 * it;
        const int n = min(nbase + row, NN - 1);
        const float iv = __shfl(invv, row);
        float4 v = reinterpret_cast<const float4*>(agg + (size_t)n * HID)[lr];
        v.x *= iv; v.y *= iv; v.z *= iv; v.w *= iv;
        *reinterpret_cast<uint2*>(&sAct[w][row][ND + lr * 4]) = pack4(v);
    }
    __syncthreads();

    short8 A[2][4];
    #pragma unroll
    for (int mt = 0; mt < 2; ++mt)
        #pragma unroll
        for (int ks = 0; ks < 4; ++ks)
            A[mt][ks] = *reinterpret_cast<const short8*>(&sAct[w][mt * 16 + lr][ks * 32 + 8 * lg]);
    #pragma unroll
    for (int nt = 0; nt < 4; ++nt) {
        const int cB = nt * 16 + lr;
        short8 B[4];
        #pragma unroll
        for (int ks = 0; ks < 4; ++ks)
            B[ks] = *reinterpret_cast<const short8*>(&sW1t[cB][ks * 32 + 8 * lg]);
        const float bv = sUB1[cB];
        #pragma unroll
        for (int mt = 0; mt < 2; ++mt) {
            f32x4 acc = (f32x4){bv, bv, bv, bv};
            #pragma unroll
            for (int ks = 0; ks < 4; ++ks)
                acc = __builtin_amdgcn_mfma_f32_16x16x32_bf16(A[mt][ks], B[ks], acc, 0, 0, 0);
            const int rH = mt * 16 + 4 * lg;
            #pragma unroll
            for (int r = 0; r < 4; ++r)
                sAct[w][rH + r][cB] = bf16r(fmaxf(acc[r], 0.0f));
        }
    }

    f32x4 o[2][4];
    #pragma unroll
    for (int nt = 0; nt < 4; ++nt) {
        const float v = sUB2[nt * 16 + lr];
        o[0][nt] = (f32x4){v, v, v, v};
        o[1][nt] = (f32x4){v, v, v, v};
    }
    #pragma unroll
    for (int mt = 0; mt < 2; ++mt) {
        const short8 A0 = *reinterpret_cast<const short8*>(&sAct[w][mt * 16 + lr][ 0 + 8 * lg]);
        const short8 A1 = *reinterpret_cast<const short8*>(&sAct[w][mt * 16 + lr][32 + 8 * lg]);
        #pragma unroll
        for (int nt = 0; nt < 4; ++nt) {
            const int cB = nt * 16 + lr;
            const short8 B0 = *reinterpret_cast<const short8*>(&sW2t[cB][ 0 + 8 * lg]);
            const short8 B1 = *reinterpret_cast<const short8*>(&sW2t[cB][32 + 8 * lg]);
            o[mt][nt] = __builtin_amdgcn_mfma_f32_16x16x32_bf16(A0, B0, o[mt][nt], 0, 0, 0);
            o[mt][nt] = __builtin_amdgcn_mfma_f32_16x16x32_bf16(A1, B1, o[mt][nt], 0, 0, 0);
        }
    }

    #pragma unroll
    for (int mt = 0; mt < 2; ++mt)
        #pragma unroll
        for (int r = 0; r < 4; ++r) {
            const int n = nbase + mt * 16 + 4 * lg + r;
            if (n < NN) {
                float* rowp = out + (size_t)n * ND;
                #pragma unroll
                for (int nt = 0; nt < 4; ++nt)
                    rowp[nt * 16 + lr] = o[mt][nt][r];
            }
        }
}

extern "C" void kernel_launch(void* const* d_in, const int* in_sizes, int n_in,
                              void* d_out, int out_size, void* d_ws, size_t ws_size,
                              hipStream_t stream)
{
    const float* nf  = (const float*)d_in[0];
    const float* ef  = (const float*)d_in[1];
    const float* w1  = (const float*)d_in[2];
    const float* b1  = (const float*)d_in[3];
    const float* w2  = (const float*)d_in[4];
    const float* b2  = (const float*)d_in[5];
    const float* uw1 = (const float*)d_in[6];
    const float* ub1 = (const float*)d_in[7];
    const float* uw2 = (const float*)d_in[8];
    const float* ub2 = (const float*)d_in[9];
    const int*   src = (const int*)d_in[10];
    const int*   dst = (const int*)d_in[11];
    float* out = (float*)d_out;

    constexpr size_t ESDB = (size_t)NE * 16;           // 12.8 MB (int4 per edge)
    constexpr size_t OFFB = (size_t)(NN + 1) * 4 + 12;
    constexpr size_t CNTB = (size_t)NN * 4;
    constexpr size_t BSUMB = 1024;
    constexpr size_t AGGB = (size_t)NN * HID * 4;      // 12.8 MB
    constexpr size_t NEED = ESDB + OFFB + CNTB + BSUMB + AGGB;

    if (ws_size >= NEED) {
        char* p = (char*)d_ws;
        int4* esd  = (int4*)p;             p += ESDB;
        int*  off  = (int*)p;              p += OFFB;
        int*  cnt  = (int*)p;              p += CNTB;   // also cursor
        int*  bsum = (int*)p;              p += BSUMB;
        float* agg = (float*)p;

        (void)hipMemsetAsync(cnt, 0, CNTB, stream);
        hist_kernel<<<NE / 256, 256, 0, stream>>>(dst, cnt);
        scanA_kernel<<<NB_SCAN, 256, 0, stream>>>(cnt, off, bsum);
        scanC_kernel<<<NB_SCAN, 256, 0, stream>>>(bsum, off, cnt);   // scanB folded in
        fill_kernel<<<NE / 256, 256, 0, stream>>>(src, dst, cnt, esd,
                                                  (float4*)agg);
        msg_kernel<1><<<NBLK, 256, 0, stream>>>(nf, ef, w1, b1, w2, b2, src, dst,
                                                esd, agg, nullptr);
        node_update_kernel<1><<<(NN + 63) / 64, 128, 0, stream>>>(
            nf, agg, off, nullptr, uw1, ub1, uw2, ub2, out);
    } else {
        float* agg = (float*)d_ws;                    // [NN][HID]
        float* deg = agg + (size_t)NN * HID;          // [NN]
        (void)hipMemsetAsync(d_ws, 0, ((size_t)NN * HID + NN) * sizeof(float), stream);
        msg_kernel<0><<<NBLK, 256, 0, stream>>>(nf, ef, w1, b1, w2, b2, src, dst,
                                                nullptr, agg, deg);
        node_update_kernel<0><<<(NN + 63) / 64, 128, 0, stream>>>(
            nf, agg, nullptr, deg, uw1, ub1, uw2, ub2, out);
    }
}